// Round 3
// baseline (513.195 us; speedup 1.0000x reference)
//
#include <hip/hip_runtime.h>
#include <hip/hip_bf16.h>

// SS2D fused pipeline for MI355X (gfx950). All fp32.
// K1 in_proj(+silu z) -> K2 dwconv3x3+silu(+transposed copy) -> K3 x_dbl proj
// (emits BC interleaved [l][n]) -> K4a chunk-local carries (B from global)
// -> K4b carry combine -> K4c full scan (B/C from global, du b128 LDS)
// -> K5a cross-merge -> K5b LayerNorm+gate+out_proj.

#define B_   8
#define H_   48
#define W_   48
#define DM   96
#define DIN  192
#define NST  16
#define RNK  6
#define KD   4
#define L_   (H_*W_)      // 2304
#define NCH  6
#define LC   (L_/NCH)     // 384 = 24 sub-chunks of 16

// ---------------------------------------------------------------- K1: in_proj
__global__ __launch_bounds__(256) void k1_inproj(
    const float* __restrict__ x, const float* __restrict__ w,
    float* __restrict__ xc_pre, float* __restrict__ z_silu) {
  __shared__ float xs[16][100];
  const int t = threadIdx.x;
  const long row0 = (long)blockIdx.x * 16;
  for (int idx = t; idx < 16*96; idx += 256) {
    int r = idx / 96, c = idx % 96;
    xs[r][c] = x[(row0 + r)*96 + c];
  }
  __syncthreads();
  for (int u = t; u < 2*DIN; u += 256) {
    float acc[16];
    #pragma unroll
    for (int r = 0; r < 16; ++r) acc[r] = 0.f;
    const float4* wrow = (const float4*)(w + u*96);
    #pragma unroll 4
    for (int cq = 0; cq < 24; ++cq) {
      float4 w4 = wrow[cq];
      #pragma unroll
      for (int r = 0; r < 16; ++r) {
        float4 x4 = *((const float4*)&xs[r][cq*4]);
        acc[r] = fmaf(w4.x,x4.x, fmaf(w4.y,x4.y, fmaf(w4.z,x4.z, fmaf(w4.w,x4.w, acc[r]))));
      }
    }
    if (u < DIN) {
      #pragma unroll
      for (int r = 0; r < 16; ++r) xc_pre[(row0 + r)*DIN + u] = acc[r];
    } else {
      #pragma unroll
      for (int r = 0; r < 16; ++r) {
        float v = acc[r];
        z_silu[(row0 + r)*DIN + (u - DIN)] = v / (1.f + __expf(-v));
      }
    }
  }
}

// ------------------------------------------------- K2: depthwise conv + silu
__global__ __launch_bounds__(256) void k2_conv(
    const float* __restrict__ xc_pre, const float* __restrict__ cw,
    const float* __restrict__ cb, float* __restrict__ xc, float* __restrict__ xT) {
  const int bid = blockIdx.x;
  const int tile = bid % 9; const int dc = (bid/9) % 6; const int b = bid / 54;
  const int h0 = (tile/3)*16, w0 = (tile%3)*16, d0 = dc*32;
  __shared__ float tin[32*325];
  __shared__ float tout[8][16][17];
  const int t = threadIdx.x;
  for (int idx = t; idx < 32*18*18; idx += 256) {
    int d2 = idx & 31; int rest = idx >> 5; int ww = rest % 18; int hh = rest / 18;
    int h = h0 + hh - 1, w = w0 + ww - 1;
    float v = 0.f;
    if (h >= 0 && h < H_ && w >= 0 && w < W_)
      v = xc_pre[((long)b*L_ + h*W_ + w)*DIN + d0 + d2];
    tin[d2*325 + hh*18 + ww] = v;
  }
  __syncthreads();
  const int hh = t >> 4, ww = t & 15;
  for (int oct = 0; oct < 4; ++oct) {
    #pragma unroll
    for (int q = 0; q < 8; ++q) {
      const int d2 = oct*8 + q;
      const int d = d0 + d2;
      float acc = cb[d];
      const float* k9 = &cw[d*9];
      const float* base = &tin[d2*325];
      #pragma unroll
      for (int i = 0; i < 3; ++i)
        #pragma unroll
        for (int j = 0; j < 3; ++j)
          acc = fmaf(base[(hh+i)*18 + ww + j], k9[i*3+j], acc);
      float s = acc / (1.f + __expf(-acc));
      xc[((long)b*DIN + d)*L_ + (h0+hh)*W_ + w0 + ww] = s;
      tout[q][hh][ww] = s;
    }
    __syncthreads();
    #pragma unroll
    for (int q = 0; q < 8; ++q) {
      const int d = d0 + oct*8 + q;
      float s2 = tout[q][t & 15][t >> 4];
      xT[((long)b*DIN + d)*L_ + (w0 + (t>>4))*H_ + h0 + (t & 15)] = s2;
    }
    __syncthreads();
  }
}

// ----------------------------------------------------------- K3: x_dbl proj
// dts_low kept [r][l]; B/C emitted interleaved BCln[(b,k)][l][n] = (B,C)
__global__ __launch_bounds__(256) void k3_xdbl(
    const float* __restrict__ xc, const float* __restrict__ xT,
    const float* __restrict__ xpw, float* __restrict__ dts_low,
    float* __restrict__ BCln) {
  const int bid = blockIdx.x;
  const int lt = bid % 72; const int k = (bid/72) & 3; const int b = bid / 288;
  const int l0 = lt * 32;
  __shared__ float xtile[DIN*32];
  __shared__ float wl[38*193];
  __shared__ float sBC[32*16*2];                // [l][n][{B,C}]
  const float* src = (k & 1) ? xT : xc;
  const bool flip = k >= 2;
  const int t = threadIdx.x;
  for (int idx = t; idx < DIN*32; idx += 256) {
    int d = idx >> 5, j = idx & 31;
    int pos = flip ? (L_-1 - (l0+j)) : (l0+j);
    xtile[d*32 + j] = src[((long)b*DIN + d)*L_ + pos];
  }
  for (int idx = t; idx < 38*DIN; idx += 256) {
    int c = idx / DIN, d = idx % DIN;
    wl[c*193 + d] = xpw[(k*38 + c)*DIN + d];
  }
  __syncthreads();
  for (int u = t; u < 38*8; u += 256) {
    int jq = u & 7, c = u >> 3;
    float4 acc = {0.f,0.f,0.f,0.f};
    for (int d = 0; d < DIN; ++d) {
      float wv = wl[c*193 + d];
      float4 x4 = *((const float4*)&xtile[d*32 + jq*4]);
      acc.x = fmaf(wv, x4.x, acc.x); acc.y = fmaf(wv, x4.y, acc.y);
      acc.z = fmaf(wv, x4.z, acc.z); acc.w = fmaf(wv, x4.w, acc.w);
    }
    if (c < 6) {
      *((float4*)&dts_low[((long)(b*KD + k)*RNK + c)*L_ + l0 + jq*4]) = acc;
    } else if (c < 22) {
      const int n = c - 6;
      sBC[((jq*4+0)*16 + n)*2] = acc.x;
      sBC[((jq*4+1)*16 + n)*2] = acc.y;
      sBC[((jq*4+2)*16 + n)*2] = acc.z;
      sBC[((jq*4+3)*16 + n)*2] = acc.w;
    } else {
      const int n = c - 22;
      sBC[((jq*4+0)*16 + n)*2 + 1] = acc.x;
      sBC[((jq*4+1)*16 + n)*2 + 1] = acc.y;
      sBC[((jq*4+2)*16 + n)*2 + 1] = acc.z;
      sBC[((jq*4+3)*16 + n)*2 + 1] = acc.w;
    }
  }
  __syncthreads();
  const float2* sbc2 = (const float2*)sBC;
  float2* dst = (float2*)BCln + (long)(b*KD + k)*L_*16 + (long)l0*16;
  for (int idx = t; idx < 512; idx += 256) dst[idx] = sbc2[idx];
}

// --------------------------------------------- K4a: chunk-local scan carries
// block = 128 thr = 8 d-groups x 16 n-lanes; grid = (b,k,dtile,chunk 0..4)
__global__ __launch_bounds__(128, 4) void k4a_carry(
    const float* __restrict__ xc, const float* __restrict__ xT,
    const float* __restrict__ dts_low, const float* __restrict__ BCln,
    const float* __restrict__ dtw_g, const float* __restrict__ dtb_g,
    const float* __restrict__ A_logs, float* __restrict__ carryH,
    float* __restrict__ carryP) {
  const int bid = blockIdx.x;
  const int cc = bid % (NCH-1); const int rest = bid / (NCH-1);
  const int dt = rest % 24; const int k = (rest/24) & 3; const int b = rest / 96;
  const int d0 = dt * 8;
  const int t = threadIdx.x;
  const int g = t >> 4, nj = t & 15;
  __shared__ alignas(16) float2 du[2][8][20];   // stride 20: 16B-aligned pairs, banks spread

  const int d = d0 + g;
  const float a = -__expf(A_logs[(k*DIN + d)*NST + nj]);
  float dtw[6];
  #pragma unroll
  for (int r = 0; r < 6; ++r) dtw[r] = dtw_g[(k*DIN + d)*RNK + r];
  const float dtbv = dtb_g[k*DIN + d];
  const float* src  = (k & 1) ? xT : xc;
  const bool flip = k >= 2;
  const float* bcf  = (const float*)((const float2*)BCln + (long)(b*KD + k)*L_*16);
  const float* dtlb = dts_low + (long)(b*KD + k)*RNK*L_;
  const float* ub   = src + ((long)b*DIN + d)*L_;
  const int base = cc * LC;

  auto load_chunk = [&](int c2, int pbuf) {
    const int l0 = base + c2*16;
    const int pos = flip ? (L_-1 - (l0+nj)) : (l0+nj);
    const float uu = ub[pos];
    float acc = dtbv;
    #pragma unroll
    for (int r = 0; r < 6; ++r) acc = fmaf(dtw[r], dtlb[r*L_ + l0 + nj], acc);
    const float dl = (acc > 20.f) ? acc : log1pf(__expf(acc));
    du[pbuf][g][nj] = make_float2(dl, dl*uu);
  };

  float h = 0.f, prod = 1.f;
  load_chunk(0, 0);
  for (int c2 = 0; c2 < LC/16; ++c2) {
    const int l0 = base + c2*16;
    float b_r[16];
    #pragma unroll
    for (int j = 0; j < 16; ++j) b_r[j] = bcf[((l0 + j)*16 + nj)*2];   // B half
    __syncthreads();
    if (c2 + 1 < LC/16) load_chunk(c2 + 1, (c2 + 1) & 1);
    const int pb = c2 & 1;
    #pragma unroll
    for (int m = 0; m < 8; ++m) {
      float4 dd = *((const float4*)&du[pb][g][2*m]);
      float dA0 = __expf(dd.x * a);
      h = fmaf(h, dA0, dd.y * b_r[2*m]);
      prod *= dA0;
      float dA1 = __expf(dd.z * a);
      h = fmaf(h, dA1, dd.w * b_r[2*m+1]);
      prod *= dA1;
    }
  }
  const long s = (long)(b*KD + k)*DIN + d;
  carryH[(s*NCH + cc)*16 + nj] = h;
  carryP[(s*NCH + cc)*16 + nj] = prod;
}

// ------------------------------------------------------ K4b: combine carries
__global__ __launch_bounds__(256) void k4b_combine(
    float* __restrict__ carryH, const float* __restrict__ carryP) {
  const int tid = blockIdx.x*256 + threadIdx.x;   // < 6144*16
  const int n = tid & 15; const long s = tid >> 4;
  float h = 0.f;
  #pragma unroll
  for (int c = 0; c < NCH-1; ++c) {
    const long idx = (s*NCH + c)*16 + n;
    const float ho = carryH[idx];
    const float ap = carryP[idx];
    carryH[idx] = h;
    h = fmaf(h, ap, ho);
  }
  carryH[(s*NCH + (NCH-1))*16 + n] = h;
}

// ----------------------------------------------------- K4c: full scan + y-out
__global__ __launch_bounds__(128, 4) void k4c_scan(
    const float* __restrict__ xc, const float* __restrict__ xT,
    const float* __restrict__ dts_low, const float* __restrict__ BCln,
    const float* __restrict__ dtw_g, const float* __restrict__ dtb_g,
    const float* __restrict__ A_logs, const float* __restrict__ Ds_g,
    const float* __restrict__ carryH, float* __restrict__ bufA,
    float* __restrict__ bufB) {
  const int bid = blockIdx.x;
  const int cc = bid % NCH; const int rest = bid / NCH;
  const int dt = rest % 24; const int k = (rest/24) & 3; const int b = rest / 96;
  const int d0 = dt * 8;
  const int t = threadIdx.x;
  const int g = t >> 4, nj = t & 15;
  __shared__ alignas(16) float2 du[2][8][20];

  const int d = d0 + g;
  const float a  = -__expf(A_logs[(k*DIN + d)*NST + nj]);
  const float Dv = Ds_g[k*DIN + d];
  float dtw[6];
  #pragma unroll
  for (int r = 0; r < 6; ++r) dtw[r] = dtw_g[(k*DIN + d)*RNK + r];
  const float dtbv = dtb_g[k*DIN + d];
  const float* src  = (k & 1) ? xT : xc;
  const bool flip = k >= 2;
  const float2* bcp = (const float2*)BCln + (long)(b*KD + k)*L_*16;
  const float* dtlb = dts_low + (long)(b*KD + k)*RNK*L_;
  const float* ub   = src + ((long)b*DIN + d)*L_;
  float* yb = ((k & 1) ? bufB : bufA) + (((long)b*2 + (k>>1))*DIN + d)*L_;
  const long s = (long)(b*KD + k)*DIN + d;
  const int base = cc * LC;

  float u_nxt;
  auto load_chunk = [&](int c2, int pbuf) {
    const int l0 = base + c2*16;
    const int pos = flip ? (L_-1 - (l0+nj)) : (l0+nj);
    u_nxt = ub[pos];
    float acc = dtbv;
    #pragma unroll
    for (int r = 0; r < 6; ++r) acc = fmaf(dtw[r], dtlb[r*L_ + l0 + nj], acc);
    const float dl = (acc > 20.f) ? acc : log1pf(__expf(acc));
    du[pbuf][g][nj] = make_float2(dl, dl*u_nxt);
  };

  float h = carryH[(s*NCH + cc)*16 + nj];
  load_chunk(0, 0);
  for (int c2 = 0; c2 < LC/16; ++c2) {
    const int l0 = base + c2*16;
    float2 bc_r[16];
    #pragma unroll
    for (int j = 0; j < 16; ++j) bc_r[j] = bcp[(l0 + j)*16 + nj];
    const float u_cur = u_nxt;
    __syncthreads();
    if (c2 + 1 < LC/16) load_chunk(c2 + 1, (c2 + 1) & 1);
    const int pb = c2 & 1;
    float p[16];
    #pragma unroll
    for (int m = 0; m < 8; ++m) {
      float4 dd = *((const float4*)&du[pb][g][2*m]);
      float2 b0 = bc_r[2*m], b1 = bc_r[2*m+1];
      float dA0 = __expf(dd.x * a);
      h = fmaf(h, dA0, dd.y * b0.x);
      p[2*m] = h * b0.y;
      float dA1 = __expf(dd.z * a);
      h = fmaf(h, dA1, dd.w * b1.x);
      p[2*m+1] = h * b1.y;
    }
    // register butterfly: transpose 16x16 across the 16-lane group + sum
    #pragma unroll
    for (int kk = 0; kk < 4; ++kk) {
      const int m = 1 << kk;
      const bool bb = (nj & m) != 0;
      #pragma unroll
      for (int ii = 0; ii < (16 >> (kk+1)); ++ii) {
        float x0 = p[2*ii], x1 = p[2*ii+1];
        float send = bb ? x0 : x1;
        float keep = bb ? x1 : x0;
        p[ii] = keep + __shfl_xor(send, m, 64);
      }
    }
    float y = fmaf(Dv, u_cur, p[0]);
    const int pos = flip ? (L_-1 - (l0+nj)) : (l0+nj);
    yb[pos] = y;
  }
}

// ------------------------------------------------------------ K5a: cross-merge
__global__ __launch_bounds__(256) void k5a_merge(
    const float* __restrict__ bufA, const float* __restrict__ bufB,
    float* __restrict__ ym) {
  const int bid = blockIdx.x;
  const int dc = bid % 6; const int tile = (bid/6) % 9; const int b = bid / 54;
  const int h0 = (tile/3)*16, w0 = (tile%3)*16, d0 = dc*32;
  __shared__ float acc[8644];
  const int t = threadIdx.x;
  for (int idx = t; idx < 8192; idx += 256) {
    int w = idx & 15, hh = (idx >> 4) & 15, ds = idx >> 8;
    long pos = (long)(h0+hh)*W_ + w0 + w;
    float v = bufA[(((long)b*2 + 0)*DIN + d0+ds)*L_ + pos]
            + bufA[(((long)b*2 + 1)*DIN + d0+ds)*L_ + pos];
    acc[hh*541 + w*33 + ds] = v;
  }
  __syncthreads();
  for (int idx = t; idx < 8192; idx += 256) {
    int hh = idx & 15, w = (idx >> 4) & 15, ds = idx >> 8;
    long m = (long)(w0+w)*H_ + h0 + hh;
    float v = bufB[(((long)b*2 + 0)*DIN + d0+ds)*L_ + m]
            + bufB[(((long)b*2 + 1)*DIN + d0+ds)*L_ + m];
    acc[hh*541 + w*33 + ds] += v;
  }
  __syncthreads();
  for (int idx = t; idx < 8192; idx += 256) {
    int ds = idx & 31, w = (idx >> 5) & 15, hh = idx >> 9;
    ym[((long)b*L_ + (h0+hh)*W_ + w0+w)*DIN + d0 + ds] = acc[hh*541 + w*33 + ds];
  }
}

// ----------------------------------------- K5b: LayerNorm + gate + out_proj
__global__ __launch_bounds__(256) void k5b_out(
    const float* __restrict__ ym, const float* __restrict__ zs,
    const float* __restrict__ lnw, const float* __restrict__ lnb,
    const float* __restrict__ wo, float* __restrict__ out) {
  const int bid = blockIdx.x;
  const int ch = bid & 1; const int lt = (bid >> 1) % 72; const int b = bid / 144;
  const int l0 = lt * 32;
  const int c0 = ch * 48;
  __shared__ float yt[DIN*33];
  __shared__ float wt[DIN*48];
  __shared__ float mu_s[32], rs_s[32];
  const int t = threadIdx.x;
  for (int idx = t; idx < 32*DIN; idx += 256) {
    int dd = idx % DIN, l = idx / DIN;
    yt[dd*33 + l] = ym[((long)b*L_ + l0 + l)*DIN + dd];
  }
  for (int idx = t; idx < DIN*48; idx += 256) {
    int cc = idx % 48, dd = idx / 48;
    wt[dd*48 + cc] = wo[(c0 + cc)*DIN + dd];
  }
  __syncthreads();
  {
    int l = t >> 3, s = t & 7;
    float sum = 0.f, sq = 0.f;
    for (int dd = s; dd < DIN; dd += 8) {
      float v = yt[dd*33 + l]; sum += v; sq = fmaf(v, v, sq);
    }
    #pragma unroll
    for (int o = 1; o < 8; o <<= 1) { sum += __shfl_xor(sum, o, 64); sq += __shfl_xor(sq, o, 64); }
    if (s == 0) {
      float mu = sum * (1.f/192.f);
      mu_s[l] = mu;
      rs_s[l] = rsqrtf(fmaxf(sq * (1.f/192.f) - mu*mu, 0.f) + 1e-5f);
    }
  }
  __syncthreads();
  for (int idx = t; idx < 32*DIN; idx += 256) {
    int dd = idx % DIN, l = idx / DIN;
    float v = yt[dd*33 + l];
    v = (v - mu_s[l]) * rs_s[l] * lnw[dd] + lnb[dd];
    v *= zs[((long)b*L_ + l0 + l)*DIN + dd];
    yt[dd*33 + l] = v;
  }
  __syncthreads();
  for (int u = t; u < 24*16; u += 256) {
    int cp = u % 24, lp = u / 24;
    int cc = cp*2, l = lp*2;
    float a00=0.f, a01=0.f, a10=0.f, a11=0.f;
    for (int dd = 0; dd < DIN; ++dd) {
      float2 wv = *((const float2*)&wt[dd*48 + cc]);
      float2 yv = *((const float2*)&yt[dd*33 + l]);
      a00 = fmaf(wv.x, yv.x, a00); a01 = fmaf(wv.y, yv.x, a01);
      a10 = fmaf(wv.x, yv.y, a10); a11 = fmaf(wv.y, yv.y, a11);
    }
    long ob = ((long)b*L_ + l0 + l)*DM + c0 + cc;
    *((float2*)&out[ob])      = make_float2(a00, a01);
    *((float2*)&out[ob + DM]) = make_float2(a10, a11);
  }
}

// ------------------------------------------------------------------- launcher
extern "C" void kernel_launch(void* const* d_in, const int* in_sizes, int n_in,
                              void* d_out, int out_size, void* d_ws, size_t ws_size,
                              hipStream_t stream) {
  (void)in_sizes; (void)n_in; (void)out_size; (void)ws_size;
  const float* x      = (const float*)d_in[0];
  const float* w_in   = (const float*)d_in[1];
  const float* conv_w = (const float*)d_in[2];
  const float* conv_b = (const float*)d_in[3];
  const float* xpw    = (const float*)d_in[4];
  const float* dtw    = (const float*)d_in[5];
  const float* dtb    = (const float*)d_in[6];
  const float* A_logs = (const float*)d_in[7];
  const float* Ds     = (const float*)d_in[8];
  const float* lnw    = (const float*)d_in[9];
  const float* lnb    = (const float*)d_in[10];
  const float* wout   = (const float*)d_in[11];
  float* out = (float*)d_out;
  float* ws  = (float*)d_ws;

  const long SZ_BLD = (long)B_*L_*DIN;          // 3,538,944 floats
  float* xc_pre  = ws;                          // (B,L,Din) [reused: carries, then ym]
  float* z_silu  = ws + SZ_BLD;
  float* xc      = ws + 2*SZ_BLD;
  float* xT      = ws + 3*SZ_BLD;
  float* dts_low = ws + 4*SZ_BLD;
  float* BCln    = dts_low + (long)B_*KD*RNK*L_;      // (B,K,L,16) float2
  float* bufA    = BCln + (long)B_*KD*L_*16*2;        // (B,2,Din,L)
  float* bufB    = bufA + (long)B_*2*DIN*L_;
  float* carryH  = xc_pre;                      // aliases xc_pre (dead after K2)
  float* carryP  = xc_pre + (long)6144*NCH*16;
  float* ym      = xc_pre;                      // aliases (carries dead after K4c)

  k1_inproj  <<<(B_*L_)/16,        256, 0, stream>>>(x, w_in, xc_pre, z_silu);
  k2_conv    <<<B_*6*9,            256, 0, stream>>>(xc_pre, conv_w, conv_b, xc, xT);
  k3_xdbl    <<<B_*KD*72,          256, 0, stream>>>(xc, xT, xpw, dts_low, BCln);
  k4a_carry  <<<B_*KD*24*(NCH-1),  128, 0, stream>>>(xc, xT, dts_low, BCln, dtw, dtb,
                                                     A_logs, carryH, carryP);
  k4b_combine<<<(6144*16)/256,     256, 0, stream>>>(carryH, carryP);
  k4c_scan   <<<B_*KD*24*NCH,      128, 0, stream>>>(xc, xT, dts_low, BCln, dtw, dtb,
                                                     A_logs, Ds, carryH, bufA, bufB);
  k5a_merge  <<<B_*9*6,            256, 0, stream>>>(bufA, bufB, ym);
  k5b_out    <<<B_*72*2,           256, 0, stream>>>(ym, z_silu, lnw, lnb, wout, out);
}